// Round 12
// baseline (212.071 us; speedup 1.0000x reference)
//
#include <hip/hip_runtime.h>

#define NH   12
#define ND   64
#define NHD  768   // NH*ND
#define NSEQ 4096
#define NIT  16
#define MM   256   // rows per chunk
#define NBH  192

// LDS pitches (bf16 elements) — proven <=2-way classes (stride ≡ 4 mod 32 dwords)
#define T_P  264
#define W_P  72
#define G_P  72

typedef __bf16 bf16_t;
typedef bf16_t bf16x8 __attribute__((ext_vector_type(8)));
typedef float  f32x4  __attribute__((ext_vector_type(4)));

static __device__ __forceinline__ unsigned short f2bf(float f) {
    union { __bf16 h; unsigned short u; } v; v.h = (__bf16)f; return v.u;
}
static __device__ __forceinline__ float bf2f(unsigned short u) {
    union { unsigned u32; float f; } v; v.u32 = ((unsigned)u) << 16; return v.f;
}
static __device__ __forceinline__ bf16x8 pack8(float4 a, float4 b) {
    union { unsigned short u[8]; bf16x8 v; } r;
    r.u[0] = f2bf(a.x); r.u[1] = f2bf(a.y); r.u[2] = f2bf(a.z); r.u[3] = f2bf(a.w);
    r.u[4] = f2bf(b.x); r.u[5] = f2bf(b.y); r.u[6] = f2bf(b.z); r.u[7] = f2bf(b.w);
    return r.v;
}
static __device__ __forceinline__ void barrier_lds() {
    asm volatile("s_waitcnt lgkmcnt(0)" ::: "memory");
    __builtin_amdgcn_s_barrier();
    asm volatile("" ::: "memory");
}

// ============ Kernel 1: G_t = X^T X, H_t = X^T Y (fully parallel) ============
extern "C" __global__ void __launch_bounds__(256)
ttt_gh(const float* __restrict__ kg, const float* __restrict__ vg,
       unsigned short* __restrict__ Gws, unsigned short* __restrict__ Hws)
{
    __shared__ unsigned short XT[64 * T_P] __attribute__((aligned(16)));
    __shared__ unsigned short YT[64 * T_P] __attribute__((aligned(16)));

    const int tid  = threadIdx.x;
    const int wv   = tid >> 6;      // 0..3
    const int lane = tid & 63;
    const int g    = lane >> 4;
    const int ln   = lane & 15;

    const int bid = blockIdx.x;
    const int bh  = bid >> 4;
    const int t   = bid & 15;

    const float* xb = kg + ((size_t)bh * NSEQ + t * MM) * ND;
    const float* yb = vg + ((size_t)bh * NSEQ + t * MM) * ND;

    // staging ownership: rows (sr, sr+1) and (128+sr, 129+sr), cols c0..c0+15
    const int sr = (tid & 63) << 1;
    const int c0 = (tid >> 6) << 4;

    // ---- stage XT (both halves; 16 float4 hoisted)
    {
        float4 ks[16];
        const float* p0 = xb + (size_t)sr * ND + c0;
        const float* p1 = xb + (size_t)(128 + sr) * ND + c0;
        #pragma unroll
        for (int i = 0; i < 4; ++i) {
            ks[i]      = *(const float4*)(p0 + 4 * i);
            ks[4 + i]  = *(const float4*)(p0 + ND + 4 * i);
            ks[8 + i]  = *(const float4*)(p1 + 4 * i);
            ks[12 + i] = *(const float4*)(p1 + ND + 4 * i);
        }
        #pragma unroll
        for (int half = 0; half < 2; ++half) {
            const int m0 = half * 128 + sr;
            #pragma unroll
            for (int j = 0; j < 16; ++j) {
                float lo = ((const float*)&ks[half * 8 + (j >> 2)])[j & 3];
                float hi = ((const float*)&ks[half * 8 + 4 + (j >> 2)])[j & 3];
                *(unsigned*)&XT[(c0 + j) * T_P + m0] =
                    (unsigned)f2bf(lo) | ((unsigned)f2bf(hi) << 16);
            }
        }
    }
    // ---- stage YT
    {
        float4 ks[16];
        const float* p0 = yb + (size_t)sr * ND + c0;
        const float* p1 = yb + (size_t)(128 + sr) * ND + c0;
        #pragma unroll
        for (int i = 0; i < 4; ++i) {
            ks[i]      = *(const float4*)(p0 + 4 * i);
            ks[4 + i]  = *(const float4*)(p0 + ND + 4 * i);
            ks[8 + i]  = *(const float4*)(p1 + 4 * i);
            ks[12 + i] = *(const float4*)(p1 + ND + 4 * i);
        }
        #pragma unroll
        for (int half = 0; half < 2; ++half) {
            const int m0 = half * 128 + sr;
            #pragma unroll
            for (int j = 0; j < 16; ++j) {
                float lo = ((const float*)&ks[half * 8 + (j >> 2)])[j & 3];
                float hi = ((const float*)&ks[half * 8 + 4 + (j >> 2)])[j & 3];
                *(unsigned*)&YT[(c0 + j) * T_P + m0] =
                    (unsigned)f2bf(lo) | ((unsigned)f2bf(hi) << 16);
            }
        }
    }
    barrier_lds();

    const int d0 = wv << 4;
    bf16x8 xa[8];
    #pragma unroll
    for (int kx = 0; kx < 8; ++kx)
        xa[kx] = *(const bf16x8*)&XT[(d0 + ln) * T_P + kx * 32 + g * 8];

    unsigned short* gout = Gws + ((size_t)bh * NIT + t) * 4096;
    unsigned short* hout = Hws + ((size_t)bh * NIT + t) * 4096;

    #pragma unroll
    for (int e0 = 0; e0 < 64; e0 += 16) {
        f32x4 ga = {0.f, 0.f, 0.f, 0.f};
        f32x4 ha = {0.f, 0.f, 0.f, 0.f};
        #pragma unroll
        for (int kx = 0; kx < 8; ++kx) {
            bf16x8 bg  = *(const bf16x8*)&XT[(e0 + ln) * T_P + kx * 32 + g * 8];
            bf16x8 bh_ = *(const bf16x8*)&YT[(e0 + ln) * T_P + kx * 32 + g * 8];
            ga = __builtin_amdgcn_mfma_f32_16x16x32_bf16(xa[kx], bg, ga, 0, 0, 0);
            ha = __builtin_amdgcn_mfma_f32_16x16x32_bf16(xa[kx], bh_, ha, 0, 0, 0);
        }
        #pragma unroll
        for (int j = 0; j < 4; ++j) {
            gout[(size_t)(d0 + 4 * g + j) * 64 + e0 + ln] = f2bf(ga[j]);
            hout[(size_t)(d0 + 4 * g + j) * 64 + e0 + ln] = f2bf(ha[j]);
        }
    }
}

// ============ Kernel 2: tiny scan (W recurrence) + out GEMM ============
extern "C" __global__ void __launch_bounds__(512)
ttt_scan(const float* __restrict__ qg, const unsigned short* __restrict__ Gws,
         const unsigned short* __restrict__ Hws, const float* __restrict__ Wi,
         float* __restrict__ outg)
{
    __shared__ unsigned short Gs[2][64 * G_P] __attribute__((aligned(16)));
    __shared__ unsigned short Hs[2][64 * G_P] __attribute__((aligned(16)));
    __shared__ unsigned short WB[2][64 * W_P] __attribute__((aligned(16)));

    const int tid  = threadIdx.x;
    const int wv   = tid >> 6;       // 0..7
    const int lane = tid & 63;
    const int g    = lane >> 4;
    const int ln   = lane & 15;

    const int bh = blockIdx.x;
    const int b  = bh / NH;
    const int h  = bh - b * NH;

    const float* qb = qg + (size_t)bh * NSEQ * ND;
    float* ob = outg + (size_t)b * NSEQ * NHD + h * ND;
    const unsigned short* gbase = Gws + (size_t)bh * NIT * 4096;
    const unsigned short* hbase = Hws + (size_t)bh * NIT * 4096;

    const int du = (wv & 3) << 4;    // update tile d-rows
    const int eu = (wv >> 2) << 5;   // update tile e-base (+ t2*16)
    const int rc = wv << 5;          // C: 32 out-rows per wave
    const float s = 1.0f / 16384.0f;

    // G/H staging: thread stages 16 B at row gr, cols gc..gc+7
    const int gr = tid >> 3;
    const int gc = (tid & 7) << 3;

    // ---- prologue
    float wf[8];   // wf[t2*4+j] = W[du+4g+j][eu+t2*16+ln] (f32 master)
    {
        const float* wp = Wi + (size_t)h * ND * ND;
        #pragma unroll
        for (int t2 = 0; t2 < 2; ++t2) {
            ushort4 wq; unsigned short* wqp = (unsigned short*)&wq;
            #pragma unroll
            for (int j = 0; j < 4; ++j) {
                wf[t2 * 4 + j] = wp[(size_t)(du + 4 * g + j) * ND + eu + t2 * 16 + ln];
                wqp[j] = f2bf(wf[t2 * 4 + j]);
            }
            *(ushort4*)&WB[0][(eu + t2 * 16 + ln) * W_P + du + 4 * g] = wq;
        }
    }
    {
        uint4 g0 = *(const uint4*)(gbase + (size_t)gr * 64 + gc);
        uint4 h0 = *(const uint4*)(hbase + (size_t)gr * 64 + gc);
        *(uint4*)&Gs[0][gr * G_P + gc] = g0;
        *(uint4*)&Hs[0][gr * G_P + gc] = h0;
    }
    uint4 greg, hreg;
    greg = *(const uint4*)(gbase + 4096 + (size_t)gr * 64 + gc);
    hreg = *(const uint4*)(hbase + 4096 + (size_t)gr * 64 + gc);
    float4 qr[8];
    barrier_lds();   // WB[0]=W_0, Gs/Hs[0]=G_0/H_0 visible

    int cur = 0;
    for (int t = 0; t < NIT; ++t) {
        const int nxt = cur ^ 1;

        // 1. stage G_{t+1}/H_{t+1} -> LDS[nxt]
        if (t + 1 < NIT) {
            *(uint4*)&Gs[nxt][gr * G_P + gc] = greg;
            *(uint4*)&Hs[nxt][gr * G_P + gc] = hreg;
        }
        // 2. issue G_{t+2}/H_{t+2}
        if (t + 2 < NIT) {
            greg = *(const uint4*)(gbase + (size_t)(t + 2) * 4096 + (size_t)gr * 64 + gc);
            hreg = *(const uint4*)(hbase + (size_t)(t + 2) * 4096 + (size_t)gr * 64 + gc);
        }

        // 3. update: upd = G_t * W_t ; wf -= s*(upd - H_t) ; WB[nxt] <- W_{t+1}
        #pragma unroll
        for (int t2 = 0; t2 < 2; ++t2) {
            f32x4 ga = {0.f, 0.f, 0.f, 0.f};
            #pragma unroll
            for (int kx = 0; kx < 2; ++kx) {
                bf16x8 ag = *(const bf16x8*)&Gs[cur][(du + ln) * G_P + kx * 32 + g * 8];
                bf16x8 bw = *(const bf16x8*)&WB[cur][(eu + t2 * 16 + ln) * W_P + kx * 32 + g * 8];
                ga = __builtin_amdgcn_mfma_f32_16x16x32_bf16(ag, bw, ga, 0, 0, 0);
            }
            ushort4 wq; unsigned short* wqp = (unsigned short*)&wq;
            #pragma unroll
            for (int j = 0; j < 4; ++j) {
                float hv = bf2f(Hs[cur][(du + 4 * g + j) * G_P + eu + t2 * 16 + ln]);
                wf[t2 * 4 + j] -= s * (ga[j] - hv);
                wqp[j] = f2bf(wf[t2 * 4 + j]);
            }
            *(ushort4*)&WB[nxt][(eu + t2 * 16 + ln) * W_P + du + 4 * g] = wq;
        }

        // 4. C(t-1): out = q(t-1) * W_t  (WB[cur]; qr loaded last region)
        if (t > 0) {
            #pragma unroll
            for (int ms = 0; ms < 2; ++ms) {
                bf16x8 aq0 = pack8(qr[ms * 4 + 0], qr[ms * 4 + 1]);
                bf16x8 aq1 = pack8(qr[ms * 4 + 2], qr[ms * 4 + 3]);
                #pragma unroll
                for (int et = 0; et < 4; ++et) {
                    bf16x8 w0 = *(const bf16x8*)&WB[cur][(et * 16 + ln) * W_P + g * 8];
                    bf16x8 w1 = *(const bf16x8*)&WB[cur][(et * 16 + ln) * W_P + 32 + g * 8];
                    f32x4 oc = {0.f, 0.f, 0.f, 0.f};
                    oc = __builtin_amdgcn_mfma_f32_16x16x32_bf16(aq0, w0, oc, 0, 0, 0);
                    oc = __builtin_amdgcn_mfma_f32_16x16x32_bf16(aq1, w1, oc, 0, 0, 0);
                    #pragma unroll
                    for (int j = 0; j < 4; ++j)
                        ob[((size_t)((t - 1) * MM) + rc + ms * 16 + 4 * g + j) * NHD + et * 16 + ln] = oc[j];
                }
            }
        }

        // 5. issue q(t) frags (consumed next region / epilogue; fly across barrier)
        #pragma unroll
        for (int ms = 0; ms < 2; ++ms) {
            const float* qp = qb + ((size_t)(t * MM) + rc + ms * 16 + ln) * ND;
            qr[ms * 4 + 0] = *(const float4*)(qp + g * 8);
            qr[ms * 4 + 1] = *(const float4*)(qp + g * 8 + 4);
            qr[ms * 4 + 2] = *(const float4*)(qp + 32 + g * 8);
            qr[ms * 4 + 3] = *(const float4*)(qp + 32 + g * 8 + 4);
        }

        barrier_lds();
        cur ^= 1;
    }

    // ---- epilogue: C(15) with W_16 (= WB[cur])
    #pragma unroll
    for (int ms = 0; ms < 2; ++ms) {
        bf16x8 aq0 = pack8(qr[ms * 4 + 0], qr[ms * 4 + 1]);
        bf16x8 aq1 = pack8(qr[ms * 4 + 2], qr[ms * 4 + 3]);
        #pragma unroll
        for (int et = 0; et < 4; ++et) {
            bf16x8 w0 = *(const bf16x8*)&WB[cur][(et * 16 + ln) * W_P + g * 8];
            bf16x8 w1 = *(const bf16x8*)&WB[cur][(et * 16 + ln) * W_P + 32 + g * 8];
            f32x4 oc = {0.f, 0.f, 0.f, 0.f};
            oc = __builtin_amdgcn_mfma_f32_16x16x32_bf16(aq0, w0, oc, 0, 0, 0);
            oc = __builtin_amdgcn_mfma_f32_16x16x32_bf16(aq1, w1, oc, 0, 0, 0);
            #pragma unroll
            for (int j = 0; j < 4; ++j)
                ob[((size_t)(15 * MM) + rc + ms * 16 + 4 * g + j) * NHD + et * 16 + ln] = oc[j];
        }
    }
}

extern "C" void kernel_launch(void* const* d_in, const int* in_sizes, int n_in,
                              void* d_out, int out_size, void* d_ws, size_t ws_size,
                              hipStream_t stream) {
    const float* q  = (const float*)d_in[0];
    const float* k  = (const float*)d_in[1];
    const float* v  = (const float*)d_in[2];
    const float* Wi = (const float*)d_in[3];
    float* out = (float*)d_out;

    int nbh = in_sizes[0] / (NSEQ * ND);   // 192
    unsigned short* Gws = (unsigned short*)d_ws;
    unsigned short* Hws = Gws + (size_t)nbh * NIT * 4096;

    hipLaunchKernelGGL(ttt_gh, dim3(nbh * NIT), dim3(256), 0, stream, k, v, Gws, Hws);
    hipLaunchKernelGGL(ttt_scan, dim3(nbh), dim3(512), 0, stream, q, Gws, Hws, Wi, out);
}

// Round 13
// 205.313 us; speedup vs baseline: 1.0329x; 1.0329x over previous
//
#include <hip/hip_runtime.h>

#define NH   12
#define ND   64
#define NHD  768   // NH*ND
#define NSEQ 4096
#define NIT  16
#define MM   256   // rows per chunk
#define NBH  192

// LDS pitches (bf16 elements) — proven <=2-way classes (stride ≡ 4 mod 32 dwords)
#define T_P  264
#define W_P  72
#define G_P  72

typedef __bf16 bf16_t;
typedef bf16_t bf16x8 __attribute__((ext_vector_type(8)));
typedef float  f32x4  __attribute__((ext_vector_type(4)));

static __device__ __forceinline__ unsigned short f2bf(float f) {
    union { __bf16 h; unsigned short u; } v; v.h = (__bf16)f; return v.u;
}
static __device__ __forceinline__ float bf2f(unsigned short u) {
    union { unsigned u32; float f; } v; v.u32 = ((unsigned)u) << 16; return v.f;
}
static __device__ __forceinline__ bf16x8 pack8(float4 a, float4 b) {
    union { unsigned short u[8]; bf16x8 v; } r;
    r.u[0] = f2bf(a.x); r.u[1] = f2bf(a.y); r.u[2] = f2bf(a.z); r.u[3] = f2bf(a.w);
    r.u[4] = f2bf(b.x); r.u[5] = f2bf(b.y); r.u[6] = f2bf(b.z); r.u[7] = f2bf(b.w);
    return r.v;
}
static __device__ __forceinline__ void barrier_lds() {
    asm volatile("s_waitcnt lgkmcnt(0)" ::: "memory");
    __builtin_amdgcn_s_barrier();
    asm volatile("" ::: "memory");
}

// ============ Kernel 1: G_t = X^T X, H_t = X^T Y (fully parallel) ============
// 512 threads, 67.5 KB LDS -> 2 blocks/CU = 16 waves/CU (R12 had 8: latency-bound).
// X and Y loads issued together: ONE exposed HBM latency per block, not two.
extern "C" __global__ void __launch_bounds__(512)
ttt_gh(const float* __restrict__ kg, const float* __restrict__ vg,
       unsigned short* __restrict__ Gws, unsigned short* __restrict__ Hws)
{
    __shared__ unsigned short XT[64 * T_P] __attribute__((aligned(16)));
    __shared__ unsigned short YT[64 * T_P] __attribute__((aligned(16)));

    const int tid  = threadIdx.x;
    const int wv   = tid >> 6;      // 0..7
    const int lane = tid & 63;
    const int g    = lane >> 4;
    const int ln   = lane & 15;

    const int bid = blockIdx.x;
    const int bh  = bid >> 4;
    const int t   = bid & 15;

    const float* xb = kg + ((size_t)bh * NSEQ + t * MM) * ND;
    const float* yb = vg + ((size_t)bh * NSEQ + t * MM) * ND;

    // staging ownership: rows (sr, sr+1), cols c0..c0+15  (512 threads cover 256x64)
    const int sr = (tid & 127) << 1;
    const int c0 = (tid >> 7) << 4;

    // ---- issue ALL 16 global loads, then convert (one latency exposure)
    float4 kx_[8], ky_[8];
    {
        const float* px = xb + (size_t)sr * ND + c0;
        const float* py = yb + (size_t)sr * ND + c0;
        #pragma unroll
        for (int i = 0; i < 4; ++i) {
            kx_[i]     = *(const float4*)(px + 4 * i);
            kx_[4 + i] = *(const float4*)(px + ND + 4 * i);
            ky_[i]     = *(const float4*)(py + 4 * i);
            ky_[4 + i] = *(const float4*)(py + ND + 4 * i);
        }
    }
    #pragma unroll
    for (int j = 0; j < 16; ++j) {
        float lo = ((const float*)&kx_[j >> 2])[j & 3];
        float hi = ((const float*)&kx_[4 + (j >> 2)])[j & 3];
        *(unsigned*)&XT[(c0 + j) * T_P + sr] = (unsigned)f2bf(lo) | ((unsigned)f2bf(hi) << 16);
    }
    #pragma unroll
    for (int j = 0; j < 16; ++j) {
        float lo = ((const float*)&ky_[j >> 2])[j & 3];
        float hi = ((const float*)&ky_[4 + (j >> 2)])[j & 3];
        *(unsigned*)&YT[(c0 + j) * T_P + sr] = (unsigned)f2bf(lo) | ((unsigned)f2bf(hi) << 16);
    }
    barrier_lds();

    // wave wv: d-tile = (wv&3), e-half = wv>>2  -> 32 MFMAs/wave
    const int d0 = (wv & 3) << 4;
    const int eh = wv >> 2;
    bf16x8 xa[8];
    #pragma unroll
    for (int kx = 0; kx < 8; ++kx)
        xa[kx] = *(const bf16x8*)&XT[(d0 + ln) * T_P + kx * 32 + g * 8];

    unsigned short* gout = Gws + ((size_t)bh * NIT + t) * 4096;
    unsigned short* hout = Hws + ((size_t)bh * NIT + t) * 4096;

    #pragma unroll
    for (int ei = 0; ei < 2; ++ei) {
        const int e0 = eh * 32 + ei * 16;
        f32x4 ga = {0.f, 0.f, 0.f, 0.f};
        f32x4 ha = {0.f, 0.f, 0.f, 0.f};
        #pragma unroll
        for (int kx = 0; kx < 8; ++kx) {
            bf16x8 bg  = *(const bf16x8*)&XT[(e0 + ln) * T_P + kx * 32 + g * 8];
            bf16x8 bh_ = *(const bf16x8*)&YT[(e0 + ln) * T_P + kx * 32 + g * 8];
            ga = __builtin_amdgcn_mfma_f32_16x16x32_bf16(xa[kx], bg, ga, 0, 0, 0);
            ha = __builtin_amdgcn_mfma_f32_16x16x32_bf16(xa[kx], bh_, ha, 0, 0, 0);
        }
        #pragma unroll
        for (int j = 0; j < 4; ++j) {
            gout[(size_t)(d0 + 4 * g + j) * 64 + e0 + ln] = f2bf(ga[j]);
            hout[(size_t)(d0 + 4 * g + j) * 64 + e0 + ln] = f2bf(ha[j]);
        }
    }
}

// ============ Kernel 2: tiny scan (W recurrence) + out GEMM (R12, unchanged) ============
extern "C" __global__ void __launch_bounds__(512)
ttt_scan(const float* __restrict__ qg, const unsigned short* __restrict__ Gws,
         const unsigned short* __restrict__ Hws, const float* __restrict__ Wi,
         float* __restrict__ outg)
{
    __shared__ unsigned short Gs[2][64 * G_P] __attribute__((aligned(16)));
    __shared__ unsigned short Hs[2][64 * G_P] __attribute__((aligned(16)));
    __shared__ unsigned short WB[2][64 * W_P] __attribute__((aligned(16)));

    const int tid  = threadIdx.x;
    const int wv   = tid >> 6;       // 0..7
    const int lane = tid & 63;
    const int g    = lane >> 4;
    const int ln   = lane & 15;

    const int bh = blockIdx.x;
    const int b  = bh / NH;
    const int h  = bh - b * NH;

    const float* qb = qg + (size_t)bh * NSEQ * ND;
    float* ob = outg + (size_t)b * NSEQ * NHD + h * ND;
    const unsigned short* gbase = Gws + (size_t)bh * NIT * 4096;
    const unsigned short* hbase = Hws + (size_t)bh * NIT * 4096;

    const int du = (wv & 3) << 4;    // update tile d-rows
    const int eu = (wv >> 2) << 5;   // update tile e-base (+ t2*16)
    const int rc = wv << 5;          // C: 32 out-rows per wave
    const float s = 1.0f / 16384.0f;

    // G/H staging: thread stages 16 B at row gr, cols gc..gc+7
    const int gr = tid >> 3;
    const int gc = (tid & 7) << 3;

    // ---- prologue
    float wf[8];   // wf[t2*4+j] = W[du+4g+j][eu+t2*16+ln] (f32 master)
    {
        const float* wp = Wi + (size_t)h * ND * ND;
        #pragma unroll
        for (int t2 = 0; t2 < 2; ++t2) {
            ushort4 wq; unsigned short* wqp = (unsigned short*)&wq;
            #pragma unroll
            for (int j = 0; j < 4; ++j) {
                wf[t2 * 4 + j] = wp[(size_t)(du + 4 * g + j) * ND + eu + t2 * 16 + ln];
                wqp[j] = f2bf(wf[t2 * 4 + j]);
            }
            *(ushort4*)&WB[0][(eu + t2 * 16 + ln) * W_P + du + 4 * g] = wq;
        }
    }
    {
        uint4 g0 = *(const uint4*)(gbase + (size_t)gr * 64 + gc);
        uint4 h0 = *(const uint4*)(hbase + (size_t)gr * 64 + gc);
        *(uint4*)&Gs[0][gr * G_P + gc] = g0;
        *(uint4*)&Hs[0][gr * G_P + gc] = h0;
    }
    uint4 greg, hreg;
    greg = *(const uint4*)(gbase + 4096 + (size_t)gr * 64 + gc);
    hreg = *(const uint4*)(hbase + 4096 + (size_t)gr * 64 + gc);
    float4 qr[8];
    barrier_lds();   // WB[0]=W_0, Gs/Hs[0]=G_0/H_0 visible

    int cur = 0;
    for (int t = 0; t < NIT; ++t) {
        const int nxt = cur ^ 1;

        // 1. stage G_{t+1}/H_{t+1} -> LDS[nxt]
        if (t + 1 < NIT) {
            *(uint4*)&Gs[nxt][gr * G_P + gc] = greg;
            *(uint4*)&Hs[nxt][gr * G_P + gc] = hreg;
        }
        // 2. issue G_{t+2}/H_{t+2}
        if (t + 2 < NIT) {
            greg = *(const uint4*)(gbase + (size_t)(t + 2) * 4096 + (size_t)gr * 64 + gc);
            hreg = *(const uint4*)(hbase + (size_t)(t + 2) * 4096 + (size_t)gr * 64 + gc);
        }

        // 3. update: upd = G_t * W_t ; wf -= s*(upd - H_t) ; WB[nxt] <- W_{t+1}
        #pragma unroll
        for (int t2 = 0; t2 < 2; ++t2) {
            f32x4 ga = {0.f, 0.f, 0.f, 0.f};
            #pragma unroll
            for (int kx = 0; kx < 2; ++kx) {
                bf16x8 ag = *(const bf16x8*)&Gs[cur][(du + ln) * G_P + kx * 32 + g * 8];
                bf16x8 bw = *(const bf16x8*)&WB[cur][(eu + t2 * 16 + ln) * W_P + kx * 32 + g * 8];
                ga = __builtin_amdgcn_mfma_f32_16x16x32_bf16(ag, bw, ga, 0, 0, 0);
            }
            ushort4 wq; unsigned short* wqp = (unsigned short*)&wq;
            #pragma unroll
            for (int j = 0; j < 4; ++j) {
                float hv = bf2f(Hs[cur][(du + 4 * g + j) * G_P + eu + t2 * 16 + ln]);
                wf[t2 * 4 + j] -= s * (ga[j] - hv);
                wqp[j] = f2bf(wf[t2 * 4 + j]);
            }
            *(ushort4*)&WB[nxt][(eu + t2 * 16 + ln) * W_P + du + 4 * g] = wq;
        }

        // 4. C(t-1): out = q(t-1) * W_t  (WB[cur]; qr loaded last region)
        if (t > 0) {
            #pragma unroll
            for (int ms = 0; ms < 2; ++ms) {
                bf16x8 aq0 = pack8(qr[ms * 4 + 0], qr[ms * 4 + 1]);
                bf16x8 aq1 = pack8(qr[ms * 4 + 2], qr[ms * 4 + 3]);
                #pragma unroll
                for (int et = 0; et < 4; ++et) {
                    bf16x8 w0 = *(const bf16x8*)&WB[cur][(et * 16 + ln) * W_P + g * 8];
                    bf16x8 w1 = *(const bf16x8*)&WB[cur][(et * 16 + ln) * W_P + 32 + g * 8];
                    f32x4 oc = {0.f, 0.f, 0.f, 0.f};
                    oc = __builtin_amdgcn_mfma_f32_16x16x32_bf16(aq0, w0, oc, 0, 0, 0);
                    oc = __builtin_amdgcn_mfma_f32_16x16x32_bf16(aq1, w1, oc, 0, 0, 0);
                    #pragma unroll
                    for (int j = 0; j < 4; ++j)
                        ob[((size_t)((t - 1) * MM) + rc + ms * 16 + 4 * g + j) * NHD + et * 16 + ln] = oc[j];
                }
            }
        }

        // 5. issue q(t) frags (consumed next region / epilogue; fly across barrier)
        #pragma unroll
        for (int ms = 0; ms < 2; ++ms) {
            const float* qp = qb + ((size_t)(t * MM) + rc + ms * 16 + ln) * ND;
            qr[ms * 4 + 0] = *(const float4*)(qp + g * 8);
            qr[ms * 4 + 1] = *(const float4*)(qp + g * 8 + 4);
            qr[ms * 4 + 2] = *(const float4*)(qp + 32 + g * 8);
            qr[ms * 4 + 3] = *(const float4*)(qp + 32 + g * 8 + 4);
        }

        barrier_lds();
        cur ^= 1;
    }

    // ---- epilogue: C(15) with W_16 (= WB[cur])
    #pragma unroll
    for (int ms = 0; ms < 2; ++ms) {
        bf16x8 aq0 = pack8(qr[ms * 4 + 0], qr[ms * 4 + 1]);
        bf16x8 aq1 = pack8(qr[ms * 4 + 2], qr[ms * 4 + 3]);
        #pragma unroll
        for (int et = 0; et < 4; ++et) {
            bf16x8 w0 = *(const bf16x8*)&WB[cur][(et * 16 + ln) * W_P + g * 8];
            bf16x8 w1 = *(const bf16x8*)&WB[cur][(et * 16 + ln) * W_P + 32 + g * 8];
            f32x4 oc = {0.f, 0.f, 0.f, 0.f};
            oc = __builtin_amdgcn_mfma_f32_16x16x32_bf16(aq0, w0, oc, 0, 0, 0);
            oc = __builtin_amdgcn_mfma_f32_16x16x32_bf16(aq1, w1, oc, 0, 0, 0);
            #pragma unroll
            for (int j = 0; j < 4; ++j)
                ob[((size_t)(15 * MM) + rc + ms * 16 + 4 * g + j) * NHD + et * 16 + ln] = oc[j];
        }
    }
}

extern "C" void kernel_launch(void* const* d_in, const int* in_sizes, int n_in,
                              void* d_out, int out_size, void* d_ws, size_t ws_size,
                              hipStream_t stream) {
    const float* q  = (const float*)d_in[0];
    const float* k  = (const float*)d_in[1];
    const float* v  = (const float*)d_in[2];
    const float* Wi = (const float*)d_in[3];
    float* out = (float*)d_out;

    int nbh = in_sizes[0] / (NSEQ * ND);   // 192
    unsigned short* Gws = (unsigned short*)d_ws;
    unsigned short* Hws = Gws + (size_t)nbh * NIT * 4096;

    hipLaunchKernelGGL(ttt_gh, dim3(nbh * NIT), dim3(512), 0, stream, k, v, Gws, Hws);
    hipLaunchKernelGGL(ttt_scan, dim3(nbh), dim3(512), 0, stream, q, Gws, Hws, Wi, out);
}